// Round 1
// baseline (679.246 us; speedup 1.0000x reference)
//
#include <hip/hip_runtime.h>

// Problem constants (fixed by setup_inputs)
#define NXc 16384
#define DHc 128          // d_hidden
#define DLc 64           // d_latent
#define Kc  3            // neighbor radius
#define Wc  (2*Kc+1)     // 7 offsets
#define Pc  32           // points per block
#define NTc 256          // threads per block
#define HALO (Pc + 2*Kc) // 38
#define DHP (DHc + 4)    // padded LDS row: breaks 4-way bank conflicts on row-broadcast reads

__device__ __forceinline__ float gelu_f(float v) {
    // exact (approximate=False) GELU: x * 0.5 * (1 + erf(x/sqrt(2)))
    return 0.5f * v * (1.0f + erff(v * 0.70710678118654752f));
}

__device__ __forceinline__ float4 f4fma(float s, float4 w, float4 a) {
    a.x = fmaf(s, w.x, a.x);
    a.y = fmaf(s, w.y, a.y);
    a.z = fmaf(s, w.z, a.z);
    a.w = fmaf(s, w.w, a.w);
    return a;
}

__global__ __launch_bounds__(NTc, 2)
void lifting_kernel(const float* __restrict__ u0, const float* __restrict__ x,
                    const float* __restrict__ nw1, const float* __restrict__ nb1,
                    const float* __restrict__ nw2, const float* __restrict__ nb2,
                    const float* __restrict__ ew1, const float* __restrict__ eb1,
                    const float* __restrict__ ew2, const float* __restrict__ eb2,
                    const float* __restrict__ cw1, const float* __restrict__ cb1,
                    const float* __restrict__ cw2, const float* __restrict__ cb2,
                    float* __restrict__ out)
{
    __shared__ float s_u[HALO], s_x[HALO];
    __shared__ float s_c[HALO][DHc];    // c_j = u_j*W1 + x_j*W2   (halo)
    __shared__ float s_gn[Pc][DHP];     // gelu(node hidden); reused as h2 in phase D
    __shared__ float s_s[Pc][DHP];      // sum_o gelu(a_i + c_{i+o} + eb1)
    __shared__ float s_hc[Pc][DHP];     // concat[h_self, agg]

    const int tid   = threadIdx.x;
    const int tiles = NXc / Pc;              // 512
    const int b     = blockIdx.x / tiles;
    const int i0    = (blockIdx.x % tiles) * Pc;
    const float* ub = u0 + (size_t)b * NXc;
    const float* xb = x  + (size_t)b * NXc;

    // ---- Phase 0: halo load of u, x with clamped indices (matches jnp.clip) ----
    if (tid < HALO) {
        int i = i0 - Kc + tid;
        i = i < 0 ? 0 : (i >= NXc ? NXc - 1 : i);
        s_u[tid] = ub[i];
        s_x[tid] = xb[i];
    }
    __syncthreads();

    // ---- Phase A: c_j for halo; gelu(node hidden) for the P points ----
    for (int idx = tid; idx < HALO * DHc; idx += NTc) {
        int t = idx >> 7, j = idx & (DHc - 1);
        s_c[t][j] = fmaf(s_u[t], ew1[DHc + j], s_x[t] * ew1[2 * DHc + j]);
    }
    for (int idx = tid; idx < Pc * DHc; idx += NTc) {
        int p = idx >> 7, j = idx & (DHc - 1);
        float pre = fmaf(s_u[p + Kc], nw1[j], fmaf(s_x[p + Kc], nw1[DHc + j], nb1[j]));
        s_gn[p][j] = gelu_f(pre);
    }
    __syncthreads();

    // ---- Phase B: s[p][j] = sum_o gelu(a_i + c_{i+o} + eb1)  (7 GELUs, 1 later matvec) ----
    for (int idx = tid; idx < Pc * DHc; idx += NTc) {
        int p = idx >> 7, j = idx & (DHc - 1);
        float a = fmaf(s_u[p + Kc], ew1[j], -(s_x[p + Kc] * ew1[2 * DHc + j])) + eb1[j];
        float acc = 0.f;
        #pragma unroll
        for (int o = 0; o < Wc; ++o)
            acc += gelu_f(a + s_c[p + o][j]);
        s_s[p][j] = acc;
    }
    __syncthreads();

    // ---- Phase C: hcat[p][0:64] = gn@nw2 + nb2 ; hcat[p][64:128] = s@ew2 + 7*eb2 ----
    {
        const int dq = tid & 15;    // 16 float4 groups -> 64 dims
        const int pg = tid >> 4;    // 16 groups -> points pg, pg+16
        const float4* nw2v = (const float4*)nw2;  // [j][dq]
        const float4* ew2v = (const float4*)ew2;
        float4 z = {0.f, 0.f, 0.f, 0.f};
        float4 aN0 = z, aN1 = z, aE0 = z, aE1 = z;
        for (int j = 0; j < DHc; ++j) {
            float4 wn = nw2v[j * 16 + dq];
            float4 we = ew2v[j * 16 + dq];
            float g0 = s_gn[pg][j],      g1 = s_gn[pg + 16][j];
            float t0 = s_s[pg][j],       t1 = s_s[pg + 16][j];
            aN0 = f4fma(g0, wn, aN0);    aN1 = f4fma(g1, wn, aN1);
            aE0 = f4fma(t0, we, aE0);    aE1 = f4fma(t1, we, aE1);
        }
        float4 bn = ((const float4*)nb2)[dq];
        float4 be = ((const float4*)eb2)[dq];
        aN0.x += bn.x; aN0.y += bn.y; aN0.z += bn.z; aN0.w += bn.w;
        aN1.x += bn.x; aN1.y += bn.y; aN1.z += bn.z; aN1.w += bn.w;
        aE0.x = fmaf(7.f, be.x, aE0.x); aE0.y = fmaf(7.f, be.y, aE0.y);
        aE0.z = fmaf(7.f, be.z, aE0.z); aE0.w = fmaf(7.f, be.w, aE0.w);
        aE1.x = fmaf(7.f, be.x, aE1.x); aE1.y = fmaf(7.f, be.y, aE1.y);
        aE1.z = fmaf(7.f, be.z, aE1.z); aE1.w = fmaf(7.f, be.w, aE1.w);
        ((float4*)&s_hc[pg][0])[dq]       = aN0;
        ((float4*)&s_hc[pg + 16][0])[dq]  = aN1;
        ((float4*)&s_hc[pg][DLc])[dq]     = aE0;
        ((float4*)&s_hc[pg + 16][DLc])[dq] = aE1;
    }
    __syncthreads();

    // ---- Phase D: h2 = gelu(hcat @ cw1 + cb1)  (128 out dims), stored over s_gn ----
    {
        const int dq = tid & 31;    // 32 float4 groups -> 128 dims
        const int pg = tid >> 5;    // 8 groups -> points pg + 8r, r=0..3
        const float4* cw1v = (const float4*)cw1;
        float4 z = {0.f, 0.f, 0.f, 0.f};
        float4 acc[4] = {z, z, z, z};
        for (int j = 0; j < DHc; ++j) {
            float4 w = cw1v[j * 32 + dq];
            #pragma unroll
            for (int r = 0; r < 4; ++r) {
                float h = s_hc[pg + 8 * r][j];
                acc[r] = f4fma(h, w, acc[r]);
            }
        }
        float4 cb = ((const float4*)cb1)[dq];
        #pragma unroll
        for (int r = 0; r < 4; ++r) {
            int p = pg + 8 * r;
            float4 v;
            v.x = gelu_f(acc[r].x + cb.x);
            v.y = gelu_f(acc[r].y + cb.y);
            v.z = gelu_f(acc[r].z + cb.z);
            v.w = gelu_f(acc[r].w + cb.w);
            ((float4*)&s_gn[p][0])[dq] = v;   // s_gn now holds h2
        }
    }
    __syncthreads();

    // ---- Phase E: out = h2 @ cw2 + cb2 ----
    {
        const int dq = tid & 15;
        const int pg = tid >> 4;
        const float4* cw2v = (const float4*)cw2;
        float4 z = {0.f, 0.f, 0.f, 0.f};
        float4 a0 = z, a1 = z;
        for (int j = 0; j < DHc; ++j) {
            float4 w = cw2v[j * 16 + dq];
            float h0 = s_gn[pg][j], h1 = s_gn[pg + 16][j];
            a0 = f4fma(h0, w, a0);
            a1 = f4fma(h1, w, a1);
        }
        float4 cb = ((const float4*)cb2)[dq];
        a0.x += cb.x; a0.y += cb.y; a0.z += cb.z; a0.w += cb.w;
        a1.x += cb.x; a1.y += cb.y; a1.z += cb.z; a1.w += cb.w;
        float4* outv = (float4*)(out + ((size_t)b * NXc + i0) * DLc);
        outv[pg * 16 + dq]        = a0;
        outv[(pg + 16) * 16 + dq] = a1;
    }
}

extern "C" void kernel_launch(void* const* d_in, const int* in_sizes, int n_in,
                              void* d_out, int out_size, void* d_ws, size_t ws_size,
                              hipStream_t stream) {
    const float* u0  = (const float*)d_in[0];
    const float* x   = (const float*)d_in[1];
    const float* nw1 = (const float*)d_in[2];
    const float* nb1 = (const float*)d_in[3];
    const float* nw2 = (const float*)d_in[4];
    const float* nb2 = (const float*)d_in[5];
    const float* ew1 = (const float*)d_in[6];
    const float* eb1 = (const float*)d_in[7];
    const float* ew2 = (const float*)d_in[8];
    const float* eb2 = (const float*)d_in[9];
    const float* cw1 = (const float*)d_in[10];
    const float* cb1 = (const float*)d_in[11];
    const float* cw2 = (const float*)d_in[12];
    const float* cb2 = (const float*)d_in[13];
    // d_in[14] is k == 3, baked in as Kc.
    float* out = (float*)d_out;

    const int Bb = 16;
    const int grid = Bb * (NXc / Pc);   // 8192 blocks
    lifting_kernel<<<grid, NTc, 0, stream>>>(u0, x, nw1, nb1, nw2, nb2,
                                             ew1, eb1, ew2, eb2,
                                             cw1, cb1, cw2, cb2, out);
}

// Round 2
// 296.367 us; speedup vs baseline: 2.2919x; 2.2919x over previous
//
#include <hip/hip_runtime.h>
#include <hip/hip_bf16.h>

// Problem constants (fixed by setup_inputs)
#define NXc 16384
#define DHc 128          // d_hidden
#define DLc 64           // d_latent
#define Kc  3            // neighbor radius
#define Wc  7            // 2k+1 offsets
#define Pc  32           // points per block
#define NTc 256          // threads per block
#define HALO 38          // Pc + 2*Kc
#define RB  272          // bf16 LDS row stride bytes: 128*2 + 16 pad (keeps 16B align, breaks bank aliasing)

typedef __attribute__((ext_vector_type(8))) short short8;   // 8 bf16 = one MFMA A/B fragment
typedef __attribute__((ext_vector_type(4))) float f32x4;    // MFMA accumulator

// LDS layout (bytes). s_hc aliases s_c (dead after phase B).
#define OFF_U  0                    // 38 fp32
#define OFF_X  160
#define OFF_C  320                  // fp32 [38][128] = 19456 -> end 19776
#define OFF_HC OFF_C                // bf16 [32] rows of RB  = 8704
#define OFF_GN 19776                // bf16 [32][RB] = 8704 -> 28480
#define OFF_S  28480                // bf16 [32][RB] = 8704 -> 37184
#define OFF_H2 37184                // bf16 [32][RB] = 8704 -> 45888
#define SMEM_BYTES 45888            // 3 blocks/CU (3*45888 = 137664 <= 163840)

// ws layout in bf16 elements (MFMA B-fragment packed): frag f=(nt*4+kt), lane l, j ->
// element W[kt*32 + (l>>4)*8 + j][nt*16 + (l&15)], stored at base + f*512 + l*8 + j
#define WS_NW2 0        // 128x64  -> 8192 elems
#define WS_EW2 8192     // 128x64
#define WS_CW1 16384    // 128x128 -> 16384 elems
#define WS_CW2 32768    // 128x64
#define WS_TOTAL 40960

__device__ __forceinline__ float gelu_f(float v) {
    return 0.5f * v * (1.0f + erff(v * 0.70710678118654752f));
}

__device__ __forceinline__ unsigned pack_bf16(float a, float b) {
    __hip_bfloat162 t;
    t.x = __float2bfloat16(a);
    t.y = __float2bfloat16(b);
    unsigned r;
    __builtin_memcpy(&r, &t, 4);
    return r;
}

// ---- prep: fp32 weights -> bf16 MFMA B-fragments in ws ----
__global__ void pack_weights(const float* __restrict__ nw2, const float* __restrict__ ew2,
                             const float* __restrict__ cw1, const float* __restrict__ cw2,
                             __hip_bfloat16* __restrict__ ws)
{
    int idx = blockIdx.x * 256 + threadIdx.x;     // 0 .. 40959
    const float* src;
    int N, base, e;
    if (idx < 8192)       { src = nw2; N = 64;  base = WS_NW2; e = idx; }
    else if (idx < 16384) { src = ew2; N = 64;  base = WS_EW2; e = idx - 8192; }
    else if (idx < 32768) { src = cw1; N = 128; base = WS_CW1; e = idx - 16384; }
    else                  { src = cw2; N = 64;  base = WS_CW2; e = idx - 32768; }
    int f = e >> 9, l = (e >> 3) & 63, j = e & 7;
    int nt = f >> 2, kt = f & 3;
    int k = kt * 32 + (l >> 4) * 8 + j;
    int n = nt * 16 + (l & 15);
    ws[base + e] = __float2bfloat16(src[k * N + n]);
}

__global__ __launch_bounds__(NTc, 3)
void lifting_mfma(const float* __restrict__ u0, const float* __restrict__ x,
                  const float* __restrict__ nw1, const float* __restrict__ nb1,
                  const float* __restrict__ nb2, const float* __restrict__ eb1,
                  const float* __restrict__ eb2, const float* __restrict__ cb1,
                  const float* __restrict__ cb2, const float* __restrict__ ew1,
                  const short8* __restrict__ wsv, float* __restrict__ out)
{
    __shared__ char sm[SMEM_BYTES];
    float* s_u = (float*)(sm + OFF_U);
    float* s_x = (float*)(sm + OFF_X);
    float* s_c = (float*)(sm + OFF_C);

    const int tid   = threadIdx.x;
    const int wave  = tid >> 6;
    const int lane  = tid & 63;
    const int quad  = lane >> 4;
    const int l15   = lane & 15;
    const int tiles = NXc / Pc;
    const int b     = blockIdx.x / tiles;
    const int i0    = (blockIdx.x % tiles) * Pc;
    const float* ub = u0 + (size_t)b * NXc;
    const float* xb = x  + (size_t)b * NXc;

    // ---- Phase 0: halo load with clamp ----
    if (tid < HALO) {
        int i = i0 - Kc + tid;
        i = i < 0 ? 0 : (i >= NXc ? NXc - 1 : i);
        s_u[tid] = ub[i];
        s_x[tid] = xb[i];
    }
    __syncthreads();

    // ---- Phase A1: c_j = u_j*ew1[1] + x_j*ew1[2] for halo (fp32) ----
    for (int idx = tid; idx < HALO * DHc; idx += NTc) {
        int t = idx >> 7, j = idx & 127;
        s_c[idx] = fmaf(s_u[t], ew1[DHc + j], s_x[t] * ew1[2 * DHc + j]);
    }
    // ---- Phase A2: gn = gelu(node hidden), bf16 pairs ----
    for (int idx = tid; idx < Pc * 64; idx += NTc) {
        int p = idx >> 6, jp = (idx & 63) * 2;
        float uu = s_u[p + Kc], xx = s_x[p + Kc];
        float p0 = fmaf(uu, nw1[jp],     fmaf(xx, nw1[DHc + jp],     nb1[jp]));
        float p1 = fmaf(uu, nw1[jp + 1], fmaf(xx, nw1[DHc + jp + 1], nb1[jp + 1]));
        *(unsigned*)(sm + OFF_GN + p * RB + jp * 2) = pack_bf16(gelu_f(p0), gelu_f(p1));
    }
    __syncthreads();

    // ---- Phase B: s = sum_o gelu(a_i + c_{i+o} + eb1), bf16 pairs ----
    for (int idx = tid; idx < Pc * 64; idx += NTc) {
        int p = idx >> 6, jp = (idx & 63) * 2;
        float uu = s_u[p + Kc], xx = s_x[p + Kc];
        float a0 = fmaf(uu, ew1[jp],     -(xx * ew1[2 * DHc + jp]))     + eb1[jp];
        float a1 = fmaf(uu, ew1[jp + 1], -(xx * ew1[2 * DHc + jp + 1])) + eb1[jp + 1];
        float acc0 = 0.f, acc1 = 0.f;
        const float* crow = s_c + p * DHc + jp;
        #pragma unroll
        for (int o = 0; o < Wc; ++o) {
            acc0 += gelu_f(a0 + crow[o * DHc]);
            acc1 += gelu_f(a1 + crow[o * DHc + 1]);
        }
        *(unsigned*)(sm + OFF_S + p * RB + jp * 2) = pack_bf16(acc0, acc1);
    }
    __syncthreads();

    // ---- Phase C (MFMA): hcat[:,0:64] = gn@nw2 + nb2 ; hcat[:,64:128] = s@ew2 + 7*eb2 ----
    {
        const int mt = wave & 1, mat = wave >> 1;
        const int rowbase = mt * 16;
        const int aoff = mat ? OFF_S : OFF_GN;
        const short8* Bmat = wsv + (mat ? (WS_EW2 >> 3) : (WS_NW2 >> 3));
        f32x4 acc[4] = {{0,0,0,0},{0,0,0,0},{0,0,0,0},{0,0,0,0}};
        #pragma unroll
        for (int kt = 0; kt < 4; ++kt) {
            short8 af = *(const short8*)(sm + aoff + (rowbase + l15) * RB + kt * 64 + quad * 16);
            #pragma unroll
            for (int nt = 0; nt < 4; ++nt) {
                short8 bf = Bmat[(nt * 4 + kt) * 64 + lane];
                acc[nt] = __builtin_amdgcn_mfma_f32_16x16x32_bf16(af, bf, acc[nt], 0, 0, 0);
            }
        }
        const float* bias = mat ? eb2 : nb2;
        const float bscale = mat ? 7.f : 1.f;
        const int colhalf = mat ? DLc : 0;
        #pragma unroll
        for (int nt = 0; nt < 4; ++nt) {
            int n = nt * 16 + l15;
            float bv = bscale * bias[n];
            #pragma unroll
            for (int r = 0; r < 4; ++r) {
                int row = rowbase + quad * 4 + r;
                *(__hip_bfloat16*)(sm + OFF_HC + row * RB + (colhalf + n) * 2) =
                    __float2bfloat16(acc[nt][r] + bv);
            }
        }
    }
    __syncthreads();

    // ---- Phase D (MFMA): h2 = gelu(hcat @ cw1 + cb1), 128 cols split 64/64 across wave pairs ----
    {
        const int mt = wave & 1, nh = wave >> 1;
        const int rowbase = mt * 16;
        const short8* Bmat = wsv + (WS_CW1 >> 3);
        f32x4 acc[4] = {{0,0,0,0},{0,0,0,0},{0,0,0,0},{0,0,0,0}};
        #pragma unroll
        for (int kt = 0; kt < 4; ++kt) {
            short8 af = *(const short8*)(sm + OFF_HC + (rowbase + l15) * RB + kt * 64 + quad * 16);
            #pragma unroll
            for (int t = 0; t < 4; ++t) {
                int nt = nh * 4 + t;
                short8 bf = Bmat[(nt * 4 + kt) * 64 + lane];
                acc[t] = __builtin_amdgcn_mfma_f32_16x16x32_bf16(af, bf, acc[t], 0, 0, 0);
            }
        }
        #pragma unroll
        for (int t = 0; t < 4; ++t) {
            int n = (nh * 4 + t) * 16 + l15;
            float cb = cb1[n];
            #pragma unroll
            for (int r = 0; r < 4; ++r) {
                int row = rowbase + quad * 4 + r;
                *(__hip_bfloat16*)(sm + OFF_H2 + row * RB + n * 2) =
                    __float2bfloat16(gelu_f(acc[t][r] + cb));
            }
        }
    }
    __syncthreads();

    // ---- Phase E (MFMA): out = h2 @ cw2 + cb2 (fp32 accumulator straight to global) ----
    {
        const int mt = wave & 1, nh = wave >> 1;
        const int rowbase = mt * 16;
        const short8* Bmat = wsv + (WS_CW2 >> 3);
        f32x4 acc[2] = {{0,0,0,0},{0,0,0,0}};
        #pragma unroll
        for (int kt = 0; kt < 4; ++kt) {
            short8 af = *(const short8*)(sm + OFF_H2 + (rowbase + l15) * RB + kt * 64 + quad * 16);
            #pragma unroll
            for (int t = 0; t < 2; ++t) {
                int nt = nh * 2 + t;
                short8 bf = Bmat[(nt * 4 + kt) * 64 + lane];
                acc[t] = __builtin_amdgcn_mfma_f32_16x16x32_bf16(af, bf, acc[t], 0, 0, 0);
            }
        }
        float* outb = out + ((size_t)b * NXc + i0) * DLc;
        #pragma unroll
        for (int t = 0; t < 2; ++t) {
            int n = (nh * 2 + t) * 16 + l15;
            float cb = cb2[n];
            #pragma unroll
            for (int r = 0; r < 4; ++r) {
                int row = rowbase + quad * 4 + r;
                outb[(size_t)row * DLc + n] = acc[t][r] + cb;
            }
        }
    }
}

extern "C" void kernel_launch(void* const* d_in, const int* in_sizes, int n_in,
                              void* d_out, int out_size, void* d_ws, size_t ws_size,
                              hipStream_t stream) {
    const float* u0  = (const float*)d_in[0];
    const float* x   = (const float*)d_in[1];
    const float* nw1 = (const float*)d_in[2];
    const float* nb1 = (const float*)d_in[3];
    const float* nw2 = (const float*)d_in[4];
    const float* nb2 = (const float*)d_in[5];
    const float* ew1 = (const float*)d_in[6];
    const float* eb1 = (const float*)d_in[7];
    const float* ew2 = (const float*)d_in[8];
    const float* eb2 = (const float*)d_in[9];
    const float* cw1 = (const float*)d_in[10];
    const float* cb1 = (const float*)d_in[11];
    const float* cw2 = (const float*)d_in[12];
    const float* cb2 = (const float*)d_in[13];
    float* out = (float*)d_out;

    __hip_bfloat16* ws = (__hip_bfloat16*)d_ws;
    pack_weights<<<WS_TOTAL / 256, 256, 0, stream>>>(nw2, ew2, cw1, cw2, ws);

    const int grid = 16 * (NXc / Pc);   // 8192 blocks
    lifting_mfma<<<grid, NTc, 0, stream>>>(u0, x, nw1, nb1, nb2, eb1, eb2, cb1, cb2,
                                           ew1, (const short8*)d_ws, out);
}

// Round 3
// 233.777 us; speedup vs baseline: 2.9055x; 1.2677x over previous
//
#include <hip/hip_runtime.h>
#include <hip/hip_bf16.h>

// Problem constants (fixed by setup_inputs)
#define NXc 16384
#define DHc 128          // d_hidden
#define DLc 64           // d_latent
#define Kc  3            // neighbor radius
#define Wc  7            // 2k+1 offsets
#define Pc  32           // points per block
#define NTc 256          // threads per block
#define HALO 38          // Pc + 2*Kc
#define RB  272          // bf16 LDS row stride bytes: 128*2 + 16 pad

typedef __attribute__((ext_vector_type(8))) short short8;   // 8 bf16 = one MFMA A/B fragment
typedef __attribute__((ext_vector_type(4))) float f32x4;    // MFMA accumulator

// LDS layout (bytes), with aliasing:
//   s_c (fp32 halo c) is dead after phase B  -> s_hc overlays it
//   s_gn is dead after phase C               -> s_h2 overlays it
#define OFF_U  0                    // 38 fp32
#define OFF_X  160
#define OFF_C  320                  // fp32 [38][128] = 19456 -> end 19776
#define OFF_HC OFF_C                // bf16 [32] rows of RB = 8704 (alias over c)
#define OFF_GN 19776                // bf16 [32][RB] = 8704 -> 28480
#define OFF_H2 OFF_GN               // h2 overlays gn (gn dead after C)
#define OFF_S  28480                // bf16 [32][RB] = 8704 -> 37184
#define SMEM_BYTES 37184            // 4 blocks/CU (4*37184 = 148736 <= 163840)

// ws layout in bf16 elements. Fragment f=(nt*4+kt), lane l, j:
// element W[kt*32 + (l>>4)*8 + j][nt*16 + (l&15)] at base + f*512 + l*8 + j.
// Used as the MFMA *A* operand => A = W^T (register-transpose trick).
#define WS_NW2 0        // 128x64
#define WS_EW2 8192     // 128x64
#define WS_CW1 16384    // 128x128
#define WS_CW2 32768    // 128x64
#define WS_TOTAL 40960

#if __has_builtin(__builtin_amdgcn_exp2f)
#define EXP2F(x) __builtin_amdgcn_exp2f(x)
#else
#define EXP2F(x) exp2f(x)
#endif
#if __has_builtin(__builtin_amdgcn_rcpf)
#define RCPF(x) __builtin_amdgcn_rcpf(x)
#else
#define RCPF(x) (1.0f / (x))
#endif

// tanh-form GELU via sigmoid: gelu(x) = x / (1 + exp2(x*(c0 + c1*x^2)))
// c0 = -2*0.7978845608*log2(e), c1 = c0*0.044715. |err vs exact erf-gelu| <~4e-4.
// Saturation is safe: exp2->inf => rcp->0 => gelu->0 (x<<0); exp2->0 => gelu->x (x>>0).
__device__ __forceinline__ float gelu_f(float v) {
    float v2 = v * v;
    float z  = v * fmaf(-0.10294325f, v2, -2.30220838f);
    float e  = EXP2F(z);
    return v * RCPF(1.0f + e);
}

__device__ __forceinline__ unsigned pack_bf16(float a, float b) {
    __hip_bfloat162 t;
    t.x = __float2bfloat16(a);
    t.y = __float2bfloat16(b);
    unsigned r;
    __builtin_memcpy(&r, &t, 4);
    return r;
}

__device__ __forceinline__ void store_bf16x4(void* p, float a, float b, float c, float d) {
    uint2 u;
    u.x = pack_bf16(a, b);
    u.y = pack_bf16(c, d);
    *(uint2*)p = u;
}

// ---- prep: fp32 weights -> bf16 MFMA fragments in ws ----
__global__ void pack_weights(const float* __restrict__ nw2, const float* __restrict__ ew2,
                             const float* __restrict__ cw1, const float* __restrict__ cw2,
                             __hip_bfloat16* __restrict__ ws)
{
    int idx = blockIdx.x * 256 + threadIdx.x;     // 0 .. 40959
    const float* src;
    int N, base, e;
    if (idx < 8192)       { src = nw2; N = 64;  base = WS_NW2; e = idx; }
    else if (idx < 16384) { src = ew2; N = 64;  base = WS_EW2; e = idx - 8192; }
    else if (idx < 32768) { src = cw1; N = 128; base = WS_CW1; e = idx - 16384; }
    else                  { src = cw2; N = 64;  base = WS_CW2; e = idx - 32768; }
    int f = e >> 9, l = (e >> 3) & 63, j = e & 7;
    int nt = f >> 2, kt = f & 3;
    int k = kt * 32 + (l >> 4) * 8 + j;
    int n = nt * 16 + (l & 15);
    ws[base + e] = __float2bfloat16(src[k * N + n]);
}

__global__ __launch_bounds__(NTc, 4)
void lifting_mfma(const float* __restrict__ u0, const float* __restrict__ x,
                  const float* __restrict__ nw1, const float* __restrict__ nb1,
                  const float* __restrict__ nb2, const float* __restrict__ eb1,
                  const float* __restrict__ eb2, const float* __restrict__ cb1,
                  const float* __restrict__ cb2, const float* __restrict__ ew1,
                  const short8* __restrict__ wsv, float* __restrict__ out)
{
    __shared__ char sm[SMEM_BYTES];
    float* s_u = (float*)(sm + OFF_U);
    float* s_x = (float*)(sm + OFF_X);
    float* s_c = (float*)(sm + OFF_C);

    const int tid   = threadIdx.x;
    const int wave  = tid >> 6;
    const int lane  = tid & 63;
    const int quad  = lane >> 4;
    const int l15   = lane & 15;
    const int tiles = NXc / Pc;
    const int b     = blockIdx.x / tiles;
    const int i0    = (blockIdx.x % tiles) * Pc;
    const float* ub = u0 + (size_t)b * NXc;
    const float* xb = x  + (size_t)b * NXc;

    // ---- Phase 0: halo load with clamp ----
    if (tid < HALO) {
        int i = i0 - Kc + tid;
        i = i < 0 ? 0 : (i >= NXc ? NXc - 1 : i);
        s_u[tid] = ub[i];
        s_x[tid] = xb[i];
    }
    __syncthreads();

    // ---- Phase A1: c_j = u_j*ew1[1] + x_j*ew1[2] for halo (fp32) ----
    for (int idx = tid; idx < HALO * DHc; idx += NTc) {
        int t = idx >> 7, j = idx & 127;
        s_c[idx] = fmaf(s_u[t], ew1[DHc + j], s_x[t] * ew1[2 * DHc + j]);
    }
    // ---- Phase A2: gn = gelu(node hidden), bf16 pairs ----
    for (int idx = tid; idx < Pc * 64; idx += NTc) {
        int p = idx >> 6, jp = (idx & 63) * 2;
        float uu = s_u[p + Kc], xx = s_x[p + Kc];
        float p0 = fmaf(uu, nw1[jp],     fmaf(xx, nw1[DHc + jp],     nb1[jp]));
        float p1 = fmaf(uu, nw1[jp + 1], fmaf(xx, nw1[DHc + jp + 1], nb1[jp + 1]));
        *(unsigned*)(sm + OFF_GN + p * RB + jp * 2) = pack_bf16(gelu_f(p0), gelu_f(p1));
    }
    __syncthreads();

    // ---- Phase B: s = sum_o gelu(a_i + c_{i+o} + eb1), bf16 pairs ----
    for (int idx = tid; idx < Pc * 64; idx += NTc) {
        int p = idx >> 6, jp = (idx & 63) * 2;
        float uu = s_u[p + Kc], xx = s_x[p + Kc];
        float a0 = fmaf(uu, ew1[jp],     -(xx * ew1[2 * DHc + jp]))     + eb1[jp];
        float a1 = fmaf(uu, ew1[jp + 1], -(xx * ew1[2 * DHc + jp + 1])) + eb1[jp + 1];
        float acc0 = 0.f, acc1 = 0.f;
        const float* crow = s_c + p * DHc + jp;
        #pragma unroll
        for (int o = 0; o < Wc; ++o) {
            acc0 += gelu_f(a0 + crow[o * DHc]);
            acc1 += gelu_f(a1 + crow[o * DHc + 1]);
        }
        *(unsigned*)(sm + OFF_S + p * RB + jp * 2) = pack_bf16(acc0, acc1);
    }
    __syncthreads();

    // ---- Phase C (MFMA, W as A-operand): D = (act@W)^T -> col=point, rows=4 consecutive features
    //      hcat[:,0:64] = gn@nw2 + nb2 ; hcat[:,64:128] = s@ew2 + 7*eb2 ----
    {
        const int mt = wave & 1, mat = wave >> 1;
        const int rowbase = mt * 16;
        const int aoff = mat ? OFF_S : OFF_GN;
        const short8* Bmat = wsv + (mat ? (WS_EW2 >> 3) : (WS_NW2 >> 3));
        f32x4 acc[4] = {{0,0,0,0},{0,0,0,0},{0,0,0,0},{0,0,0,0}};
        #pragma unroll
        for (int kt = 0; kt < 4; ++kt) {
            short8 af = *(const short8*)(sm + aoff + (rowbase + l15) * RB + kt * 64 + quad * 16);
            #pragma unroll
            for (int nt = 0; nt < 4; ++nt) {
                short8 wf = Bmat[(nt * 4 + kt) * 64 + lane];
                acc[nt] = __builtin_amdgcn_mfma_f32_16x16x32_bf16(wf, af, acc[nt], 0, 0, 0);
            }
        }
        const float* bias = mat ? eb2 : nb2;
        const float bscale = mat ? 7.f : 1.f;
        const int colhalf = mat ? DLc : 0;
        const int p = rowbase + l15;          // point this lane owns
        #pragma unroll
        for (int nt = 0; nt < 4; ++nt) {
            float4 bv = ((const float4*)bias)[nt * 4 + quad];   // features nt*16+quad*4 ..+3
            store_bf16x4(sm + OFF_HC + p * RB + (colhalf + nt * 16 + quad * 4) * 2,
                         fmaf(bscale, bv.x, acc[nt][0]),
                         fmaf(bscale, bv.y, acc[nt][1]),
                         fmaf(bscale, bv.z, acc[nt][2]),
                         fmaf(bscale, bv.w, acc[nt][3]));
        }
    }
    __syncthreads();

    // ---- Phase D (MFMA): h2 = gelu(hcat @ cw1 + cb1), feature halves across wave pairs ----
    {
        const int mt = wave & 1, nh = wave >> 1;
        const int rowbase = mt * 16;
        const short8* Bmat = wsv + (WS_CW1 >> 3);
        f32x4 acc[4] = {{0,0,0,0},{0,0,0,0},{0,0,0,0},{0,0,0,0}};
        #pragma unroll
        for (int kt = 0; kt < 4; ++kt) {
            short8 af = *(const short8*)(sm + OFF_HC + (rowbase + l15) * RB + kt * 64 + quad * 16);
            #pragma unroll
            for (int t = 0; t < 4; ++t) {
                int nt = nh * 4 + t;
                short8 wf = Bmat[(nt * 4 + kt) * 64 + lane];
                acc[t] = __builtin_amdgcn_mfma_f32_16x16x32_bf16(wf, af, acc[t], 0, 0, 0);
            }
        }
        const int p = rowbase + l15;
        #pragma unroll
        for (int t = 0; t < 4; ++t) {
            int nbase = (nh * 4 + t) * 16 + quad * 4;
            float4 cb = ((const float4*)cb1)[nbase >> 2];
            store_bf16x4(sm + OFF_H2 + p * RB + nbase * 2,
                         gelu_f(acc[t][0] + cb.x),
                         gelu_f(acc[t][1] + cb.y),
                         gelu_f(acc[t][2] + cb.z),
                         gelu_f(acc[t][3] + cb.w));
        }
    }
    __syncthreads();

    // ---- Phase E (MFMA): out = h2 @ cw2 + cb2, float4 straight to global ----
    {
        const int mt = wave & 1, nh = wave >> 1;
        const int rowbase = mt * 16;
        const short8* Bmat = wsv + (WS_CW2 >> 3);
        f32x4 acc[2] = {{0,0,0,0},{0,0,0,0}};
        #pragma unroll
        for (int kt = 0; kt < 4; ++kt) {
            short8 af = *(const short8*)(sm + OFF_H2 + (rowbase + l15) * RB + kt * 64 + quad * 16);
            #pragma unroll
            for (int t = 0; t < 2; ++t) {
                int nt = nh * 2 + t;
                short8 wf = Bmat[(nt * 4 + kt) * 64 + lane];
                acc[t] = __builtin_amdgcn_mfma_f32_16x16x32_bf16(wf, af, acc[t], 0, 0, 0);
            }
        }
        const int p = rowbase + l15;
        float* outb = out + ((size_t)b * NXc + i0 + p) * DLc;
        #pragma unroll
        for (int t = 0; t < 2; ++t) {
            int nbase = (nh * 2 + t) * 16 + quad * 4;
            float4 cb = ((const float4*)cb2)[nbase >> 2];
            float4 v;
            v.x = acc[t][0] + cb.x;
            v.y = acc[t][1] + cb.y;
            v.z = acc[t][2] + cb.z;
            v.w = acc[t][3] + cb.w;
            *(float4*)(outb + nbase) = v;
        }
    }
}

extern "C" void kernel_launch(void* const* d_in, const int* in_sizes, int n_in,
                              void* d_out, int out_size, void* d_ws, size_t ws_size,
                              hipStream_t stream) {
    const float* u0  = (const float*)d_in[0];
    const float* x   = (const float*)d_in[1];
    const float* nw1 = (const float*)d_in[2];
    const float* nb1 = (const float*)d_in[3];
    const float* nw2 = (const float*)d_in[4];
    const float* nb2 = (const float*)d_in[5];
    const float* ew1 = (const float*)d_in[6];
    const float* eb1 = (const float*)d_in[7];
    const float* ew2 = (const float*)d_in[8];
    const float* eb2 = (const float*)d_in[9];
    const float* cw1 = (const float*)d_in[10];
    const float* cb1 = (const float*)d_in[11];
    const float* cw2 = (const float*)d_in[12];
    const float* cb2 = (const float*)d_in[13];
    float* out = (float*)d_out;

    __hip_bfloat16* ws = (__hip_bfloat16*)d_ws;
    pack_weights<<<WS_TOTAL / 256, 256, 0, stream>>>(nw2, ew2, cw1, cw2, ws);

    const int grid = 16 * (NXc / Pc);   // 8192 blocks
    lifting_mfma<<<grid, NTc, 0, stream>>>(u0, x, nw1, nb1, nb2, eb1, eb2, cb1, cb2,
                                           ew1, (const short8*)d_ws, out);
}

// Round 4
// 205.779 us; speedup vs baseline: 3.3009x; 1.1361x over previous
//
#include <hip/hip_runtime.h>
#include <hip/hip_bf16.h>

// Problem constants (fixed by setup_inputs)
#define NXc 16384
#define DHc 128          // d_hidden
#define DLc 64           // d_latent
#define Kc  3            // neighbor radius
#define Wc  7            // 2k+1 offsets
#define Pc  32           // points per block
#define NTc 256          // threads per block
#define HALO 38          // Pc + 2*Kc
#define RB  272          // bf16 activation LDS row stride (128*2 + 16 pad)
#define RBc 272          // bf16 c row stride (64 pairs * 4B + 16 pad)

typedef __attribute__((ext_vector_type(8))) short short8;   // 8 bf16 = one MFMA A/B fragment
typedef __attribute__((ext_vector_type(4))) float f32x4;    // MFMA accumulator

// LDS layout (bytes), aliased:
//   s_c (bf16 halo c) dead after phase B -> s_hc overlays it
//   s_gn dead after phase C              -> s_h2 overlays it
#define OFF_U  0                    // 38 fp32 (pad to 160)
#define OFF_X  160
#define OFF_C  320                  // bf16 pairs [38][RBc] = 10336 -> end 10656
#define OFF_HC OFF_C                // bf16 [32][RB] = 8704 (alias, fits)
#define OFF_GN 10656                // bf16 [32][RB] = 8704 -> 19360
#define OFF_H2 OFF_GN               // alias (gn dead after C)
#define OFF_S  19360                // bf16 [32][RB] = 8704 -> 28064
#define SMEM_BYTES 28064            // 5 blocks/CU (5*~28.3KB <= 160KB)

// ws layout in bf16 elements. Fragment f=(nt*4+kt), lane l, j:
// element W[kt*32 + (l>>4)*8 + j][nt*16 + (l&15)] at base + f*512 + l*8 + j.
// Used as the MFMA *A* operand => D = (act@W)^T (register-transpose trick).
#define WS_NW2 0        // 128x64
#define WS_EW2 8192     // 128x64
#define WS_CW1 16384    // 128x128
#define WS_CW2 32768    // 128x64
#define WS_TOTAL 40960

#if __has_builtin(__builtin_amdgcn_exp2f)
#define EXP2F(x) __builtin_amdgcn_exp2f(x)
#else
#define EXP2F(x) exp2f(x)
#endif
#if __has_builtin(__builtin_amdgcn_rcpf)
#define RCPF(x) __builtin_amdgcn_rcpf(x)
#else
#define RCPF(x) (1.0f / (x))
#endif

// tanh-form GELU via sigmoid: gelu(x) = x / (1 + exp2(x*(c0 + c1*x^2)))
#define GC0 -2.30220838f
#define GC1 -0.10294325f

__device__ __forceinline__ float gelu_f(float v) {
    float v2 = v * v;
    float z  = v * fmaf(GC1, v2, GC0);
    float e  = EXP2F(z);
    return v * RCPF(1.0f + e);
}

// acc += gelu(v), with the final mul folded into the accumulate fma
__device__ __forceinline__ float gelu_acc(float v, float acc) {
    float v2 = v * v;
    float z  = v * fmaf(GC1, v2, GC0);
    float e  = EXP2F(z);
    float r  = RCPF(1.0f + e);
    return fmaf(v, r, acc);
}

// branchless RNE bf16 pack (inputs are never NaN here)
__device__ __forceinline__ unsigned bf16rne(float a) {
    unsigned u;
    __builtin_memcpy(&u, &a, 4);
    return u + 0x7FFFu + ((u >> 16) & 1u);
}
__device__ __forceinline__ unsigned pack_bf16(float a, float b) {
    return (bf16rne(a) >> 16) | (bf16rne(b) & 0xFFFF0000u);
}
__device__ __forceinline__ void store_bf16x4(void* p, float a, float b, float c, float d) {
    uint2 u;
    u.x = pack_bf16(a, b);
    u.y = pack_bf16(c, d);
    *(uint2*)p = u;
}
__device__ __forceinline__ float bf_lo(unsigned u) {
    unsigned v = u << 16;
    float f; __builtin_memcpy(&f, &v, 4);
    return f;
}
__device__ __forceinline__ float bf_hi(unsigned u) {
    unsigned v = u & 0xFFFF0000u;
    float f; __builtin_memcpy(&f, &v, 4);
    return f;
}

// ---- prep: fp32 weights -> bf16 MFMA fragments in ws ----
__global__ void pack_weights(const float* __restrict__ nw2, const float* __restrict__ ew2,
                             const float* __restrict__ cw1, const float* __restrict__ cw2,
                             __hip_bfloat16* __restrict__ ws)
{
    int idx = blockIdx.x * 256 + threadIdx.x;     // 0 .. 40959
    const float* src;
    int N, base, e;
    if (idx < 8192)       { src = nw2; N = 64;  base = WS_NW2; e = idx; }
    else if (idx < 16384) { src = ew2; N = 64;  base = WS_EW2; e = idx - 8192; }
    else if (idx < 32768) { src = cw1; N = 128; base = WS_CW1; e = idx - 16384; }
    else                  { src = cw2; N = 64;  base = WS_CW2; e = idx - 32768; }
    int f = e >> 9, l = (e >> 3) & 63, j = e & 7;
    int nt = f >> 2, kt = f & 3;
    int k = kt * 32 + (l >> 4) * 8 + j;
    int n = nt * 16 + (l & 15);
    ws[base + e] = __float2bfloat16(src[k * N + n]);
}

__global__ __launch_bounds__(NTc, 5)
void lifting_mfma(const float* __restrict__ u0, const float* __restrict__ x,
                  const float* __restrict__ nw1, const float* __restrict__ nb1,
                  const float* __restrict__ nb2, const float* __restrict__ eb1,
                  const float* __restrict__ eb2, const float* __restrict__ cb1,
                  const float* __restrict__ cb2, const float* __restrict__ ew1,
                  const short8* __restrict__ wsv, float* __restrict__ out)
{
    __shared__ char sm[SMEM_BYTES];
    float* s_u = (float*)(sm + OFF_U);
    float* s_x = (float*)(sm + OFF_X);

    const int tid   = threadIdx.x;
    const int wave  = tid >> 6;
    const int lane  = tid & 63;
    const int quad  = lane >> 4;
    const int l15   = lane & 15;
    const int tiles = NXc / Pc;
    const int b     = blockIdx.x / tiles;
    const int i0    = (blockIdx.x % tiles) * Pc;
    const float* ub = u0 + (size_t)b * NXc;
    const float* xb = x  + (size_t)b * NXc;

    // ---- Phase 0: halo load with clamp ----
    if (tid < HALO) {
        int i = i0 - Kc + tid;
        i = i < 0 ? 0 : (i >= NXc ? NXc - 1 : i);
        s_u[tid] = ub[i];
        s_x[tid] = xb[i];
    }
    __syncthreads();

    // ---- Phase A: c_j = u_j*ew1[1] + x_j*ew1[2] for halo, stored bf16 pairs ----
    for (int idx = tid; idx < HALO * 64; idx += NTc) {
        int t = idx >> 6, j2 = idx & 63;
        int j = j2 * 2;
        float uu = s_u[t], xx = s_x[t];
        float c0 = fmaf(uu, ew1[DHc + j],     xx * ew1[2 * DHc + j]);
        float c1 = fmaf(uu, ew1[DHc + j + 1], xx * ew1[2 * DHc + j + 1]);
        *(unsigned*)(sm + OFF_C + t * RBc + j2 * 4) = pack_bf16(c0, c1);
    }
    __syncthreads();

    // ---- Phase B (merged node+edge): per (p, 4 dims):
    //      gn = gelu(node hidden);  s = sum_o gelu(a_i + c_{i+o} + eb1) ----
    for (int idx = tid; idx < Pc * 32; idx += NTc) {   // 4 iters/thread
        int p = idx >> 5, jq = idx & 31;
        int j0 = jq * 4;
        float uu = s_u[p + Kc], xx = s_x[p + Kc];

        // node MLP first layer + gelu (bf16 to gn)
        float4 w0 = *(const float4*)(nw1 + j0);
        float4 w1 = *(const float4*)(nw1 + DHc + j0);
        float4 nb = *(const float4*)(nb1 + j0);
        float g0 = gelu_f(fmaf(uu, w0.x, fmaf(xx, w1.x, nb.x)));
        float g1 = gelu_f(fmaf(uu, w0.y, fmaf(xx, w1.y, nb.y)));
        float g2 = gelu_f(fmaf(uu, w0.z, fmaf(xx, w1.z, nb.z)));
        float g3 = gelu_f(fmaf(uu, w0.w, fmaf(xx, w1.w, nb.w)));
        store_bf16x4(sm + OFF_GN + p * RB + j0 * 2, g0, g1, g2, g3);

        // edge: a_i = u_i*W0 - x_i*W2 + b1 ; then 7-offset gelu-sum
        float4 e0 = *(const float4*)(ew1 + j0);
        float4 e2 = *(const float4*)(ew1 + 2 * DHc + j0);
        float4 be = *(const float4*)(eb1 + j0);
        float a0 = fmaf(uu, e0.x, -(xx * e2.x)) + be.x;
        float a1 = fmaf(uu, e0.y, -(xx * e2.y)) + be.y;
        float a2 = fmaf(uu, e0.z, -(xx * e2.z)) + be.z;
        float a3 = fmaf(uu, e0.w, -(xx * e2.w)) + be.w;
        float acc0 = 0.f, acc1 = 0.f, acc2 = 0.f, acc3 = 0.f;
        const char* crow = sm + OFF_C + p * RBc + jq * 8;
        #pragma unroll
        for (int o = 0; o < Wc; ++o) {
            uint2 cp = *(const uint2*)(crow + o * RBc);
            acc0 = gelu_acc(a0 + bf_lo(cp.x), acc0);
            acc1 = gelu_acc(a1 + bf_hi(cp.x), acc1);
            acc2 = gelu_acc(a2 + bf_lo(cp.y), acc2);
            acc3 = gelu_acc(a3 + bf_hi(cp.y), acc3);
        }
        store_bf16x4(sm + OFF_S + p * RB + j0 * 2, acc0, acc1, acc2, acc3);
    }
    __syncthreads();

    // ---- Phase C (MFMA, W as A-operand): D = (act@W)^T -> col=point, rows=4 consecutive features
    //      hcat[:,0:64] = gn@nw2 + nb2 ; hcat[:,64:128] = s@ew2 + 7*eb2 ----
    {
        const int mt = wave & 1, mat = wave >> 1;
        const int rowbase = mt * 16;
        const int aoff = mat ? OFF_S : OFF_GN;
        const short8* Bmat = wsv + (mat ? (WS_EW2 >> 3) : (WS_NW2 >> 3));
        f32x4 acc[4] = {{0,0,0,0},{0,0,0,0},{0,0,0,0},{0,0,0,0}};
        #pragma unroll
        for (int kt = 0; kt < 4; ++kt) {
            short8 af = *(const short8*)(sm + aoff + (rowbase + l15) * RB + kt * 64 + quad * 16);
            #pragma unroll
            for (int nt = 0; nt < 4; ++nt) {
                short8 wf = Bmat[(nt * 4 + kt) * 64 + lane];
                acc[nt] = __builtin_amdgcn_mfma_f32_16x16x32_bf16(wf, af, acc[nt], 0, 0, 0);
            }
        }
        const float* bias = mat ? eb2 : nb2;
        const float bscale = mat ? 7.f : 1.f;
        const int colhalf = mat ? DLc : 0;
        const int p = rowbase + l15;          // point this lane owns
        #pragma unroll
        for (int nt = 0; nt < 4; ++nt) {
            float4 bv = ((const float4*)bias)[nt * 4 + quad];   // features nt*16+quad*4 ..+3
            store_bf16x4(sm + OFF_HC + p * RB + (colhalf + nt * 16 + quad * 4) * 2,
                         fmaf(bscale, bv.x, acc[nt][0]),
                         fmaf(bscale, bv.y, acc[nt][1]),
                         fmaf(bscale, bv.z, acc[nt][2]),
                         fmaf(bscale, bv.w, acc[nt][3]));
        }
    }
    __syncthreads();

    // ---- Phase D (MFMA): h2 = gelu(hcat @ cw1 + cb1), feature halves across wave pairs ----
    {
        const int mt = wave & 1, nh = wave >> 1;
        const int rowbase = mt * 16;
        const short8* Bmat = wsv + (WS_CW1 >> 3);
        f32x4 acc[4] = {{0,0,0,0},{0,0,0,0},{0,0,0,0},{0,0,0,0}};
        #pragma unroll
        for (int kt = 0; kt < 4; ++kt) {
            short8 af = *(const short8*)(sm + OFF_HC + (rowbase + l15) * RB + kt * 64 + quad * 16);
            #pragma unroll
            for (int t = 0; t < 4; ++t) {
                int nt = nh * 4 + t;
                short8 wf = Bmat[(nt * 4 + kt) * 64 + lane];
                acc[t] = __builtin_amdgcn_mfma_f32_16x16x32_bf16(wf, af, acc[t], 0, 0, 0);
            }
        }
        const int p = rowbase + l15;
        #pragma unroll
        for (int t = 0; t < 4; ++t) {
            int nbase = (nh * 4 + t) * 16 + quad * 4;
            float4 cb = ((const float4*)cb1)[nbase >> 2];
            store_bf16x4(sm + OFF_H2 + p * RB + nbase * 2,
                         gelu_f(acc[t][0] + cb.x),
                         gelu_f(acc[t][1] + cb.y),
                         gelu_f(acc[t][2] + cb.z),
                         gelu_f(acc[t][3] + cb.w));
        }
    }
    __syncthreads();

    // ---- Phase E (MFMA): out = h2 @ cw2 + cb2, float4 straight to global ----
    {
        const int mt = wave & 1, nh = wave >> 1;
        const int rowbase = mt * 16;
        const short8* Bmat = wsv + (WS_CW2 >> 3);
        f32x4 acc[2] = {{0,0,0,0},{0,0,0,0}};
        #pragma unroll
        for (int kt = 0; kt < 4; ++kt) {
            short8 af = *(const short8*)(sm + OFF_H2 + (rowbase + l15) * RB + kt * 64 + quad * 16);
            #pragma unroll
            for (int t = 0; t < 2; ++t) {
                int nt = nh * 2 + t;
                short8 wf = Bmat[(nt * 4 + kt) * 64 + lane];
                acc[t] = __builtin_amdgcn_mfma_f32_16x16x32_bf16(wf, af, acc[t], 0, 0, 0);
            }
        }
        const int p = rowbase + l15;
        float* outb = out + ((size_t)b * NXc + i0 + p) * DLc;
        #pragma unroll
        for (int t = 0; t < 2; ++t) {
            int nbase = (nh * 2 + t) * 16 + quad * 4;
            float4 cb = ((const float4*)cb2)[nbase >> 2];
            float4 v;
            v.x = acc[t][0] + cb.x;
            v.y = acc[t][1] + cb.y;
            v.z = acc[t][2] + cb.z;
            v.w = acc[t][3] + cb.w;
            *(float4*)(outb + nbase) = v;
        }
    }
}

extern "C" void kernel_launch(void* const* d_in, const int* in_sizes, int n_in,
                              void* d_out, int out_size, void* d_ws, size_t ws_size,
                              hipStream_t stream) {
    const float* u0  = (const float*)d_in[0];
    const float* x   = (const float*)d_in[1];
    const float* nw1 = (const float*)d_in[2];
    const float* nb1 = (const float*)d_in[3];
    const float* nw2 = (const float*)d_in[4];
    const float* nb2 = (const float*)d_in[5];
    const float* ew1 = (const float*)d_in[6];
    const float* eb1 = (const float*)d_in[7];
    const float* ew2 = (const float*)d_in[8];
    const float* eb2 = (const float*)d_in[9];
    const float* cw1 = (const float*)d_in[10];
    const float* cb1 = (const float*)d_in[11];
    const float* cw2 = (const float*)d_in[12];
    const float* cb2 = (const float*)d_in[13];
    float* out = (float*)d_out;

    __hip_bfloat16* ws = (__hip_bfloat16*)d_ws;
    pack_weights<<<WS_TOTAL / 256, 256, 0, stream>>>(nw2, ew2, cw1, cw2, ws);

    const int grid = 16 * (NXc / Pc);   // 8192 blocks
    lifting_mfma<<<grid, NTc, 0, stream>>>(u0, x, nw1, nb1, nb2, eb1, eb2, cb1, cb2,
                                           ew1, (const short8*)d_ws, out);
}

// Round 5
// 202.776 us; speedup vs baseline: 3.3497x; 1.0148x over previous
//
#include <hip/hip_runtime.h>
#include <hip/hip_bf16.h>

// Problem constants (fixed by setup_inputs)
#define NXc 16384
#define DHc 128          // d_hidden
#define DLc 64           // d_latent
#define Kc  3            // neighbor radius
#define Wc  7            // 2k+1 offsets
#define Pc  32           // points per block
#define NTc 256          // threads per block
#define HALO 38          // Pc + 2*Kc
#define RB  272          // bf16 activation LDS row stride (128*2 + 16 pad)
#define RBc 272          // bf16 c row stride (64 pairs * 4B + 16 pad)

typedef __attribute__((ext_vector_type(8))) short short8;   // 8 bf16 = one MFMA A/B fragment
typedef __attribute__((ext_vector_type(4))) float f32x4;    // MFMA accumulator

// LDS layout (bytes), aliased:
//   s_c (bf16 halo c) dead after phase B -> s_hc overlays it
//   s_gn dead after phase C              -> s_h2 overlays it
#define OFF_U  0                    // 38 fp32 (pad to 160)
#define OFF_X  160
#define OFF_C  320                  // bf16 pairs [38][RBc] = 10336 -> end 10656
#define OFF_HC OFF_C                // bf16 [32][RB] = 8704 (alias, fits)
#define OFF_GN 10656                // bf16 [32][RB] = 8704 -> 19360
#define OFF_H2 OFF_GN               // alias (gn dead after C)
#define OFF_S  19360                // bf16 [32][RB] = 8704 -> 28064
#define SMEM_BYTES 28064            // 5 blocks/CU

// ws layout in bf16 elements. Fragment f=(nt*4+kt), lane l, j:
// element W[kt*32 + (l>>4)*8 + j][nt*16 + (l&15)] at base + f*512 + l*8 + j.
// Used as the MFMA *A* operand => D = (act@W)^T (register-transpose trick).
#define WS_NW2 0        // 128x64
#define WS_EW2 8192     // 128x64
#define WS_CW1 16384    // 128x128
#define WS_CW2 32768    // 128x64
#define WS_TOTAL 40960

#if __has_builtin(__builtin_amdgcn_exp2f)
#define EXP2F(x) __builtin_amdgcn_exp2f(x)
#else
#define EXP2F(x) exp2f(x)
#endif
#if __has_builtin(__builtin_amdgcn_rcpf)
#define RCPF(x) __builtin_amdgcn_rcpf(x)
#else
#define RCPF(x) (1.0f / (x))
#endif

// tanh-form GELU via sigmoid: gelu(x) = x / (1 + exp2(x*(c0 + c1*x^2)))
#define GC0 -2.30220838f
#define GC1 -0.10294325f

// Paired gelu: ONE rcp for two gelus (exact): r = rcp(t0*t1); g0 = x0*t1*r; g1 = x1*t0*r.
// Inputs clamped at -8 (gelu(-8) ~ 3e-21 ~ 0) so t0*t1 stays in safe fp32 range.
__device__ __forceinline__ void gelu2(float x0, float x1, float& g0, float& g1) {
    x0 = fmaxf(x0, -8.0f);
    x1 = fmaxf(x1, -8.0f);
    float e0 = EXP2F(x0 * fmaf(GC1, x0 * x0, GC0));
    float e1 = EXP2F(x1 * fmaf(GC1, x1 * x1, GC0));
    float t0 = 1.0f + e0, t1 = 1.0f + e1;
    float rr = RCPF(t0 * t1);
    g0 = x0 * t1 * rr;
    g1 = x1 * t0 * rr;
}

// acc0 += gelu(x0), acc1 += gelu(x1) with one shared rcp.
// Phase-B edge args are analytically bounded (|x| <~ 2.6) -> no clamp needed.
__device__ __forceinline__ void gelu2_acc(float x0, float x1, float& a0, float& a1) {
    float e0 = EXP2F(x0 * fmaf(GC1, x0 * x0, GC0));
    float e1 = EXP2F(x1 * fmaf(GC1, x1 * x1, GC0));
    float t0 = 1.0f + e0, t1 = 1.0f + e1;
    float rr = RCPF(t0 * t1);
    a0 = fmaf(x0 * t1, rr, a0);
    a1 = fmaf(x1 * t0, rr, a1);
}

// branchless RNE bf16 pack (inputs are never NaN here)
__device__ __forceinline__ unsigned bf16rne(float a) {
    unsigned u;
    __builtin_memcpy(&u, &a, 4);
    return u + 0x7FFFu + ((u >> 16) & 1u);
}
__device__ __forceinline__ unsigned pack_bf16(float a, float b) {
    return (bf16rne(a) >> 16) | (bf16rne(b) & 0xFFFF0000u);
}
__device__ __forceinline__ void store_bf16x4(void* p, float a, float b, float c, float d) {
    uint2 u;
    u.x = pack_bf16(a, b);
    u.y = pack_bf16(c, d);
    *(uint2*)p = u;
}
__device__ __forceinline__ float bf_lo(unsigned u) {
    unsigned v = u << 16;
    float f; __builtin_memcpy(&f, &v, 4);
    return f;
}
__device__ __forceinline__ float bf_hi(unsigned u) {
    unsigned v = u & 0xFFFF0000u;
    float f; __builtin_memcpy(&f, &v, 4);
    return f;
}

// ---- prep: fp32 weights -> bf16 MFMA fragments in ws ----
__global__ void pack_weights(const float* __restrict__ nw2, const float* __restrict__ ew2,
                             const float* __restrict__ cw1, const float* __restrict__ cw2,
                             __hip_bfloat16* __restrict__ ws)
{
    int idx = blockIdx.x * 256 + threadIdx.x;     // 0 .. 40959
    const float* src;
    int N, base, e;
    if (idx < 8192)       { src = nw2; N = 64;  base = WS_NW2; e = idx; }
    else if (idx < 16384) { src = ew2; N = 64;  base = WS_EW2; e = idx - 8192; }
    else if (idx < 32768) { src = cw1; N = 128; base = WS_CW1; e = idx - 16384; }
    else                  { src = cw2; N = 64;  base = WS_CW2; e = idx - 32768; }
    int f = e >> 9, l = (e >> 3) & 63, j = e & 7;
    int nt = f >> 2, kt = f & 3;
    int k = kt * 32 + (l >> 4) * 8 + j;
    int n = nt * 16 + (l & 15);
    ws[base + e] = __float2bfloat16(src[k * N + n]);
}

__global__ __launch_bounds__(NTc, 5)
void lifting_mfma(const float* __restrict__ u0, const float* __restrict__ x,
                  const float* __restrict__ nw1, const float* __restrict__ nb1,
                  const float* __restrict__ nb2, const float* __restrict__ eb1,
                  const float* __restrict__ eb2, const float* __restrict__ cb1,
                  const float* __restrict__ cb2, const float* __restrict__ ew1,
                  const short8* __restrict__ wsv, float* __restrict__ out)
{
    __shared__ char sm[SMEM_BYTES];
    float* s_u = (float*)(sm + OFF_U);
    float* s_x = (float*)(sm + OFF_X);

    const int tid   = threadIdx.x;
    const int wave  = tid >> 6;
    const int lane  = tid & 63;
    const int quad  = lane >> 4;
    const int l15   = lane & 15;
    const int tiles = NXc / Pc;
    const int b     = blockIdx.x / tiles;
    const int i0    = (blockIdx.x % tiles) * Pc;
    const float* ub = u0 + (size_t)b * NXc;
    const float* xb = x  + (size_t)b * NXc;

    // ---- Phase 0: halo load with clamp ----
    if (tid < HALO) {
        int i = i0 - Kc + tid;
        i = i < 0 ? 0 : (i >= NXc ? NXc - 1 : i);
        s_u[tid] = ub[i];
        s_x[tid] = xb[i];
    }
    __syncthreads();

    // ---- Phase A: c_j = u_j*ew1[1] + x_j*ew1[2] for halo, bf16 pairs.
    //      Thread keeps a fixed dim-pair -> weight loads hoisted out of the row loop. ----
    {
        const int j2 = tid & 63;          // dim pair 0..63
        const int r0 = tid >> 6;          // row start 0..3
        const int j  = j2 * 2;
        float2 wa = *(const float2*)(ew1 + DHc + j);
        float2 wb = *(const float2*)(ew1 + 2 * DHc + j);
        for (int t = r0; t < HALO; t += 4) {
            float uu = s_u[t], xx = s_x[t];
            float c0 = fmaf(uu, wa.x, xx * wb.x);
            float c1 = fmaf(uu, wa.y, xx * wb.y);
            *(unsigned*)(sm + OFF_C + t * RBc + j2 * 4) = pack_bf16(c0, c1);
        }
    }
    __syncthreads();

    // ---- Phase B (merged node+edge): thread owns dim-quad jq for 4 points;
    //      all 6 weight float4s hoisted. ----
    {
        const int jq = tid & 31, pbase = tid >> 5;
        const int j0 = jq * 4;
        const float4 w0 = *(const float4*)(nw1 + j0);
        const float4 w1 = *(const float4*)(nw1 + DHc + j0);
        const float4 nb = *(const float4*)(nb1 + j0);
        const float4 e0 = *(const float4*)(ew1 + j0);
        const float4 e2 = *(const float4*)(ew1 + 2 * DHc + j0);
        const float4 be = *(const float4*)(eb1 + j0);
        #pragma unroll
        for (int r = 0; r < 4; ++r) {
            const int p = pbase + 8 * r;
            const float uu = s_u[p + Kc], xx = s_x[p + Kc];

            // node MLP first layer + gelu (bf16 to gn)
            float g0, g1, g2, g3;
            gelu2(fmaf(uu, w0.x, fmaf(xx, w1.x, nb.x)),
                  fmaf(uu, w0.y, fmaf(xx, w1.y, nb.y)), g0, g1);
            gelu2(fmaf(uu, w0.z, fmaf(xx, w1.z, nb.z)),
                  fmaf(uu, w0.w, fmaf(xx, w1.w, nb.w)), g2, g3);
            store_bf16x4(sm + OFF_GN + p * RB + j0 * 2, g0, g1, g2, g3);

            // edge: a_i = u_i*W0 - x_i*W2 + b1 ; then 7-offset gelu-sum
            float a0 = fmaf(uu, e0.x, -(xx * e2.x)) + be.x;
            float a1 = fmaf(uu, e0.y, -(xx * e2.y)) + be.y;
            float a2 = fmaf(uu, e0.z, -(xx * e2.z)) + be.z;
            float a3 = fmaf(uu, e0.w, -(xx * e2.w)) + be.w;
            float acc0 = 0.f, acc1 = 0.f, acc2 = 0.f, acc3 = 0.f;
            const char* crow = sm + OFF_C + p * RBc + jq * 8;
            #pragma unroll
            for (int o = 0; o < Wc; ++o) {
                uint2 cp = *(const uint2*)(crow + o * RBc);
                gelu2_acc(a0 + bf_lo(cp.x), a1 + bf_hi(cp.x), acc0, acc1);
                gelu2_acc(a2 + bf_lo(cp.y), a3 + bf_hi(cp.y), acc2, acc3);
            }
            store_bf16x4(sm + OFF_S + p * RB + j0 * 2, acc0, acc1, acc2, acc3);
        }
    }
    __syncthreads();

    // ---- Phase C (MFMA, W as A-operand): D = (act@W)^T -> col=point, rows=4 consecutive features
    //      hcat[:,0:64] = gn@nw2 + nb2 ; hcat[:,64:128] = s@ew2 + 7*eb2 ----
    {
        const int mt = wave & 1, mat = wave >> 1;
        const int rowbase = mt * 16;
        const int aoff = mat ? OFF_S : OFF_GN;
        const short8* Bmat = wsv + (mat ? (WS_EW2 >> 3) : (WS_NW2 >> 3));
        f32x4 acc[4] = {{0,0,0,0},{0,0,0,0},{0,0,0,0},{0,0,0,0}};
        #pragma unroll
        for (int kt = 0; kt < 4; ++kt) {
            short8 af = *(const short8*)(sm + aoff + (rowbase + l15) * RB + kt * 64 + quad * 16);
            #pragma unroll
            for (int nt = 0; nt < 4; ++nt) {
                short8 wf = Bmat[(nt * 4 + kt) * 64 + lane];
                acc[nt] = __builtin_amdgcn_mfma_f32_16x16x32_bf16(wf, af, acc[nt], 0, 0, 0);
            }
        }
        const float* bias = mat ? eb2 : nb2;
        const float bscale = mat ? 7.f : 1.f;
        const int colhalf = mat ? DLc : 0;
        const int p = rowbase + l15;          // point this lane owns
        #pragma unroll
        for (int nt = 0; nt < 4; ++nt) {
            float4 bv = ((const float4*)bias)[nt * 4 + quad];   // features nt*16+quad*4 ..+3
            store_bf16x4(sm + OFF_HC + p * RB + (colhalf + nt * 16 + quad * 4) * 2,
                         fmaf(bscale, bv.x, acc[nt][0]),
                         fmaf(bscale, bv.y, acc[nt][1]),
                         fmaf(bscale, bv.z, acc[nt][2]),
                         fmaf(bscale, bv.w, acc[nt][3]));
        }
    }
    __syncthreads();

    // ---- Phase D (MFMA): h2 = gelu(hcat @ cw1 + cb1), feature halves across wave pairs ----
    {
        const int mt = wave & 1, nh = wave >> 1;
        const int rowbase = mt * 16;
        const short8* Bmat = wsv + (WS_CW1 >> 3);
        f32x4 acc[4] = {{0,0,0,0},{0,0,0,0},{0,0,0,0},{0,0,0,0}};
        #pragma unroll
        for (int kt = 0; kt < 4; ++kt) {
            short8 af = *(const short8*)(sm + OFF_HC + (rowbase + l15) * RB + kt * 64 + quad * 16);
            #pragma unroll
            for (int t = 0; t < 4; ++t) {
                int nt = nh * 4 + t;
                short8 wf = Bmat[(nt * 4 + kt) * 64 + lane];
                acc[t] = __builtin_amdgcn_mfma_f32_16x16x32_bf16(wf, af, acc[t], 0, 0, 0);
            }
        }
        const int p = rowbase + l15;
        #pragma unroll
        for (int t = 0; t < 4; ++t) {
            int nbase = (nh * 4 + t) * 16 + quad * 4;
            float4 cb = ((const float4*)cb1)[nbase >> 2];
            float h0, h1, h2v, h3;
            gelu2(acc[t][0] + cb.x, acc[t][1] + cb.y, h0, h1);
            gelu2(acc[t][2] + cb.z, acc[t][3] + cb.w, h2v, h3);
            store_bf16x4(sm + OFF_H2 + p * RB + nbase * 2, h0, h1, h2v, h3);
        }
    }
    __syncthreads();

    // ---- Phase E (MFMA): out = h2 @ cw2 + cb2, float4 straight to global ----
    {
        const int mt = wave & 1, nh = wave >> 1;
        const int rowbase = mt * 16;
        const short8* Bmat = wsv + (WS_CW2 >> 3);
        f32x4 acc[2] = {{0,0,0,0},{0,0,0,0}};
        #pragma unroll
        for (int kt = 0; kt < 4; ++kt) {
            short8 af = *(const short8*)(sm + OFF_H2 + (rowbase + l15) * RB + kt * 64 + quad * 16);
            #pragma unroll
            for (int t = 0; t < 2; ++t) {
                int nt = nh * 2 + t;
                short8 wf = Bmat[(nt * 4 + kt) * 64 + lane];
                acc[t] = __builtin_amdgcn_mfma_f32_16x16x32_bf16(wf, af, acc[t], 0, 0, 0);
            }
        }
        const int p = rowbase + l15;
        float* outb = out + ((size_t)b * NXc + i0 + p) * DLc;
        #pragma unroll
        for (int t = 0; t < 2; ++t) {
            int nbase = (nh * 2 + t) * 16 + quad * 4;
            float4 cb = ((const float4*)cb2)[nbase >> 2];
            float4 v;
            v.x = acc[t][0] + cb.x;
            v.y = acc[t][1] + cb.y;
            v.z = acc[t][2] + cb.z;
            v.w = acc[t][3] + cb.w;
            *(float4*)(outb + nbase) = v;
        }
    }
}

extern "C" void kernel_launch(void* const* d_in, const int* in_sizes, int n_in,
                              void* d_out, int out_size, void* d_ws, size_t ws_size,
                              hipStream_t stream) {
    const float* u0  = (const float*)d_in[0];
    const float* x   = (const float*)d_in[1];
    const float* nw1 = (const float*)d_in[2];
    const float* nb1 = (const float*)d_in[3];
    const float* nw2 = (const float*)d_in[4];
    const float* nb2 = (const float*)d_in[5];
    const float* ew1 = (const float*)d_in[6];
    const float* eb1 = (const float*)d_in[7];
    const float* ew2 = (const float*)d_in[8];
    const float* eb2 = (const float*)d_in[9];
    const float* cw1 = (const float*)d_in[10];
    const float* cb1 = (const float*)d_in[11];
    const float* cw2 = (const float*)d_in[12];
    const float* cb2 = (const float*)d_in[13];
    float* out = (float*)d_out;

    __hip_bfloat16* ws = (__hip_bfloat16*)d_ws;
    pack_weights<<<WS_TOTAL / 256, 256, 0, stream>>>(nw2, ew2, cw1, cw2, ws);

    const int grid = 16 * (NXc / Pc);   // 8192 blocks
    lifting_mfma<<<grid, NTc, 0, stream>>>(u0, x, nw1, nb1, nb2, eb1, eb2, cb1, cb2,
                                           ew1, (const short8*)d_ws, out);
}

// Round 6
// 198.630 us; speedup vs baseline: 3.4197x; 1.0209x over previous
//
#include <hip/hip_runtime.h>
#include <hip/hip_bf16.h>

// Problem constants (fixed by setup_inputs)
#define NXc 16384
#define DHc 128          // d_hidden
#define DLc 64           // d_latent
#define Kc  3            // neighbor radius
#define Wc  7            // 2k+1 offsets
#define Pc  32           // points per block
#define NTc 256          // threads per block
#define HALO 38          // Pc + 2*Kc
#define RB  272          // bf16 activation LDS row stride (128*2 + 16 pad)

typedef __attribute__((ext_vector_type(8))) short short8;   // 8 bf16 = one MFMA A/B fragment
typedef __attribute__((ext_vector_type(4))) float f32x4;    // MFMA accumulator

// LDS layout (bytes). c is registerized (no LDS array). H2 overlays GN (dead after C).
#define OFF_U  0                    // 38 fp32 (pad to 160)
#define OFF_X  160                  // -> 320
#define OFF_GN 320                  // bf16 [32][RB] = 8704 -> 9024
#define OFF_H2 OFF_GN               // alias (gn dead after C)
#define OFF_S  9024                 // bf16 [32][RB] = 8704 -> 17728
#define OFF_HC 17728                // bf16 [32][RB] = 8704 -> 26432
#define SMEM_BYTES 26432            // 6 blocks/CU (6*26432 = 158592 <= 163840)

// ws layout in bf16 elements. Fragment f=(nt*4+kt), lane l, j:
// element W[kt*32 + (l>>4)*8 + j][nt*16 + (l&15)] at base + f*512 + l*8 + j.
// Used as the MFMA *A* operand => D = (act@W)^T (register-transpose trick).
#define WS_NW2 0        // 128x64
#define WS_EW2 8192     // 128x64
#define WS_CW1 16384    // 128x128
#define WS_CW2 32768    // 128x64
#define WS_TOTAL 40960

#if __has_builtin(__builtin_amdgcn_exp2f)
#define EXP2F(x) __builtin_amdgcn_exp2f(x)
#else
#define EXP2F(x) exp2f(x)
#endif
#if __has_builtin(__builtin_amdgcn_rcpf)
#define RCPF(x) __builtin_amdgcn_rcpf(x)
#else
#define RCPF(x) (1.0f / (x))
#endif

// tanh-form GELU via sigmoid: gelu(x) = x / (1 + exp2(x*(c0 + c1*x^2)))
#define GC0 -2.30220838f
#define GC1 -0.10294325f

// Paired gelu: ONE rcp for two gelus (exact): r = rcp(t0*t1); g0 = x0*t1*r; g1 = x1*t0*r.
// Inputs clamped at -8 (gelu(-8) ~ 3e-21 ~ 0) so exp2 can't overflow into NaN paths.
__device__ __forceinline__ void gelu2(float x0, float x1, float& g0, float& g1) {
    x0 = fmaxf(x0, -8.0f);
    x1 = fmaxf(x1, -8.0f);
    float e0 = EXP2F(x0 * fmaf(GC1, x0 * x0, GC0));
    float e1 = EXP2F(x1 * fmaf(GC1, x1 * x1, GC0));
    float t0 = 1.0f + e0, t1 = 1.0f + e1;
    float rr = RCPF(t0 * t1);
    g0 = x0 * t1 * rr;
    g1 = x1 * t0 * rr;
}

// acc0 += gelu(x0), acc1 += gelu(x1) with one shared rcp.
// Phase-B edge args are analytically bounded (|x| <~ 3) -> no clamp needed.
__device__ __forceinline__ void gelu2_acc(float x0, float x1, float& a0, float& a1) {
    float e0 = EXP2F(x0 * fmaf(GC1, x0 * x0, GC0));
    float e1 = EXP2F(x1 * fmaf(GC1, x1 * x1, GC0));
    float t0 = 1.0f + e0, t1 = 1.0f + e1;
    float rr = RCPF(t0 * t1);
    a0 = fmaf(x0 * t1, rr, a0);
    a1 = fmaf(x1 * t0, rr, a1);
}

// bf16 pair pack: HW v_cvt_pk_bf16_f32 (gfx950) when available, else branchless RNE.
#if __has_builtin(__builtin_amdgcn_cvt_pk_bf16_f32)
typedef __attribute__((ext_vector_type(2))) __bf16 bf16x2_t;
__device__ __forceinline__ unsigned pack_bf16(float a, float b) {
    bf16x2_t v = __builtin_amdgcn_cvt_pk_bf16_f32(a, b);   // lo = src0, hi = src1
    unsigned r; __builtin_memcpy(&r, &v, 4); return r;
}
#else
__device__ __forceinline__ unsigned bf16rne(float a) {
    unsigned u;
    __builtin_memcpy(&u, &a, 4);
    return u + 0x7FFFu + ((u >> 16) & 1u);
}
__device__ __forceinline__ unsigned pack_bf16(float a, float b) {
    return (bf16rne(a) >> 16) | (bf16rne(b) & 0xFFFF0000u);
}
#endif
__device__ __forceinline__ void store_bf16x4(void* p, float a, float b, float c, float d) {
    uint2 u;
    u.x = pack_bf16(a, b);
    u.y = pack_bf16(c, d);
    *(uint2*)p = u;
}

// ---- prep: fp32 weights -> bf16 MFMA fragments in ws ----
__global__ void pack_weights(const float* __restrict__ nw2, const float* __restrict__ ew2,
                             const float* __restrict__ cw1, const float* __restrict__ cw2,
                             __hip_bfloat16* __restrict__ ws)
{
    int idx = blockIdx.x * 256 + threadIdx.x;     // 0 .. 40959
    const float* src;
    int N, base, e;
    if (idx < 8192)       { src = nw2; N = 64;  base = WS_NW2; e = idx; }
    else if (idx < 16384) { src = ew2; N = 64;  base = WS_EW2; e = idx - 8192; }
    else if (idx < 32768) { src = cw1; N = 128; base = WS_CW1; e = idx - 16384; }
    else                  { src = cw2; N = 64;  base = WS_CW2; e = idx - 32768; }
    int f = e >> 9, l = (e >> 3) & 63, j = e & 7;
    int nt = f >> 2, kt = f & 3;
    int k = kt * 32 + (l >> 4) * 8 + j;
    int n = nt * 16 + (l & 15);
    ws[base + e] = __float2bfloat16(src[k * N + n]);
}

__global__ __launch_bounds__(NTc, 6)
void lifting_mfma(const float* __restrict__ u0, const float* __restrict__ x,
                  const float* __restrict__ nw1, const float* __restrict__ nb1,
                  const float* __restrict__ nb2, const float* __restrict__ eb1,
                  const float* __restrict__ eb2, const float* __restrict__ cb1,
                  const float* __restrict__ cb2, const float* __restrict__ ew1,
                  const short8* __restrict__ wsv, float* __restrict__ out)
{
    __shared__ char sm[SMEM_BYTES];
    float* s_u = (float*)(sm + OFF_U);
    float* s_x = (float*)(sm + OFF_X);

    const int tid   = threadIdx.x;
    const int wave  = tid >> 6;
    const int lane  = tid & 63;
    const int quad  = lane >> 4;
    const int l15   = lane & 15;
    const int tiles = NXc / Pc;
    const int b     = blockIdx.x / tiles;
    const int i0    = (blockIdx.x % tiles) * Pc;
    const float* ub = u0 + (size_t)b * NXc;
    const float* xb = x  + (size_t)b * NXc;

    // ---- Phase 0: halo load with clamp ----
    if (tid < HALO) {
        int i = i0 - Kc + tid;
        i = i < 0 ? 0 : (i >= NXc ? NXc - 1 : i);
        s_u[tid] = ub[i];
        s_x[tid] = xb[i];
    }
    __syncthreads();

    // ---- Phase B (fused): thread owns dim-quad jq for 4 CONSECUTIVE points.
    //      The 7-neighbor c-window of 4 consecutive points = 10 rows, computed in
    //      registers (fp32) -- no c LDS array, no phase-A barrier. ----
    {
        const int jq = tid & 31;           // dim quad 0..31
        const int pbase = (tid >> 5) * 4;  // points pbase..pbase+3
        const int j0 = jq * 4;
        const float4 w0 = *(const float4*)(nw1 + j0);
        const float4 w1 = *(const float4*)(nw1 + DHc + j0);
        const float4 nb = *(const float4*)(nb1 + j0);
        const float4 e0 = *(const float4*)(ew1 + j0);
        const float4 e1 = *(const float4*)(ew1 + DHc + j0);
        const float4 e2 = *(const float4*)(ew1 + 2 * DHc + j0);
        const float4 be = *(const float4*)(eb1 + j0);

        float su[10], sx[10];
        #pragma unroll
        for (int r = 0; r < 10; ++r) {
            su[r] = s_u[pbase + r];        // halo rows pbase-3+Kc .. pbase+6+Kc
            sx[r] = s_x[pbase + r];
        }

        float cw[10][4];                   // c_j window, fp32
        #pragma unroll
        for (int r = 0; r < 10; ++r) {
            cw[r][0] = fmaf(su[r], e1.x, sx[r] * e2.x);
            cw[r][1] = fmaf(su[r], e1.y, sx[r] * e2.y);
            cw[r][2] = fmaf(su[r], e1.z, sx[r] * e2.z);
            cw[r][3] = fmaf(su[r], e1.w, sx[r] * e2.w);
        }

        #pragma unroll
        for (int r0 = 0; r0 < 4; ++r0) {
            const int p = pbase + r0;
            const float uu = su[r0 + 3], xx = sx[r0 + 3];

            // node MLP first layer + gelu -> gn (bf16)
            float g0, g1, g2, g3;
            gelu2(fmaf(uu, w0.x, fmaf(xx, w1.x, nb.x)),
                  fmaf(uu, w0.y, fmaf(xx, w1.y, nb.y)), g0, g1);
            gelu2(fmaf(uu, w0.z, fmaf(xx, w1.z, nb.z)),
                  fmaf(uu, w0.w, fmaf(xx, w1.w, nb.w)), g2, g3);
            store_bf16x4(sm + OFF_GN + p * RB + j0 * 2, g0, g1, g2, g3);

            // edge: a_i = u_i*W0 - x_i*W2 + b1 ; 7-offset gelu-sum from register window
            float a0 = fmaf(uu, e0.x, -(xx * e2.x)) + be.x;
            float a1 = fmaf(uu, e0.y, -(xx * e2.y)) + be.y;
            float a2 = fmaf(uu, e0.z, -(xx * e2.z)) + be.z;
            float a3 = fmaf(uu, e0.w, -(xx * e2.w)) + be.w;
            float acc0 = 0.f, acc1 = 0.f, acc2 = 0.f, acc3 = 0.f;
            #pragma unroll
            for (int o = 0; o < Wc; ++o) {
                const float* cr = cw[r0 + o];
                gelu2_acc(a0 + cr[0], a1 + cr[1], acc0, acc1);
                gelu2_acc(a2 + cr[2], a3 + cr[3], acc2, acc3);
            }
            store_bf16x4(sm + OFF_S + p * RB + j0 * 2, acc0, acc1, acc2, acc3);
        }
    }
    __syncthreads();

    // ---- Phase C (MFMA, W as A-operand): D = (act@W)^T -> col=point, rows=4 consecutive features
    //      hcat[:,0:64] = gn@nw2 + nb2 ; hcat[:,64:128] = s@ew2 + 7*eb2 ----
    {
        const int mt = wave & 1, mat = wave >> 1;
        const int rowbase = mt * 16;
        const int aoff = mat ? OFF_S : OFF_GN;
        const short8* Bmat = wsv + (mat ? (WS_EW2 >> 3) : (WS_NW2 >> 3));
        f32x4 acc[4] = {{0,0,0,0},{0,0,0,0},{0,0,0,0},{0,0,0,0}};
        #pragma unroll
        for (int kt = 0; kt < 4; ++kt) {
            short8 af = *(const short8*)(sm + aoff + (rowbase + l15) * RB + kt * 64 + quad * 16);
            #pragma unroll
            for (int nt = 0; nt < 4; ++nt) {
                short8 wf = Bmat[(nt * 4 + kt) * 64 + lane];
                acc[nt] = __builtin_amdgcn_mfma_f32_16x16x32_bf16(wf, af, acc[nt], 0, 0, 0);
            }
        }
        const float* bias = mat ? eb2 : nb2;
        const float bscale = mat ? 7.f : 1.f;
        const int colhalf = mat ? DLc : 0;
        const int p = rowbase + l15;          // point this lane owns
        #pragma unroll
        for (int nt = 0; nt < 4; ++nt) {
            float4 bv = ((const float4*)bias)[nt * 4 + quad];   // features nt*16+quad*4 ..+3
            store_bf16x4(sm + OFF_HC + p * RB + (colhalf + nt * 16 + quad * 4) * 2,
                         fmaf(bscale, bv.x, acc[nt][0]),
                         fmaf(bscale, bv.y, acc[nt][1]),
                         fmaf(bscale, bv.z, acc[nt][2]),
                         fmaf(bscale, bv.w, acc[nt][3]));
        }
    }
    __syncthreads();

    // ---- Phase D (MFMA): h2 = gelu(hcat @ cw1 + cb1), feature halves across wave pairs ----
    {
        const int mt = wave & 1, nh = wave >> 1;
        const int rowbase = mt * 16;
        const short8* Bmat = wsv + (WS_CW1 >> 3);
        f32x4 acc[4] = {{0,0,0,0},{0,0,0,0},{0,0,0,0},{0,0,0,0}};
        #pragma unroll
        for (int kt = 0; kt < 4; ++kt) {
            short8 af = *(const short8*)(sm + OFF_HC + (rowbase + l15) * RB + kt * 64 + quad * 16);
            #pragma unroll
            for (int t = 0; t < 4; ++t) {
                int nt = nh * 4 + t;
                short8 wf = Bmat[(nt * 4 + kt) * 64 + lane];
                acc[t] = __builtin_amdgcn_mfma_f32_16x16x32_bf16(wf, af, acc[t], 0, 0, 0);
            }
        }
        const int p = rowbase + l15;
        #pragma unroll
        for (int t = 0; t < 4; ++t) {
            int nbase = (nh * 4 + t) * 16 + quad * 4;
            float4 cb = ((const float4*)cb1)[nbase >> 2];
            float h0, h1, h2v, h3;
            gelu2(acc[t][0] + cb.x, acc[t][1] + cb.y, h0, h1);
            gelu2(acc[t][2] + cb.z, acc[t][3] + cb.w, h2v, h3);
            store_bf16x4(sm + OFF_H2 + p * RB + nbase * 2, h0, h1, h2v, h3);
        }
    }
    __syncthreads();

    // ---- Phase E (MFMA): out = h2 @ cw2 + cb2, float4 straight to global ----
    {
        const int mt = wave & 1, nh = wave >> 1;
        const int rowbase = mt * 16;
        const short8* Bmat = wsv + (WS_CW2 >> 3);
        f32x4 acc[2] = {{0,0,0,0},{0,0,0,0}};
        #pragma unroll
        for (int kt = 0; kt < 4; ++kt) {
            short8 af = *(const short8*)(sm + OFF_H2 + (rowbase + l15) * RB + kt * 64 + quad * 16);
            #pragma unroll
            for (int t = 0; t < 2; ++t) {
                int nt = nh * 2 + t;
                short8 wf = Bmat[(nt * 4 + kt) * 64 + lane];
                acc[t] = __builtin_amdgcn_mfma_f32_16x16x32_bf16(wf, af, acc[t], 0, 0, 0);
            }
        }
        const int p = rowbase + l15;
        float* outb = out + ((size_t)b * NXc + i0 + p) * DLc;
        #pragma unroll
        for (int t = 0; t < 2; ++t) {
            int nbase = (nh * 2 + t) * 16 + quad * 4;
            float4 cb = ((const float4*)cb2)[nbase >> 2];
            float4 v;
            v.x = acc[t][0] + cb.x;
            v.y = acc[t][1] + cb.y;
            v.z = acc[t][2] + cb.z;
            v.w = acc[t][3] + cb.w;
            *(float4*)(outb + nbase) = v;
        }
    }
}

extern "C" void kernel_launch(void* const* d_in, const int* in_sizes, int n_in,
                              void* d_out, int out_size, void* d_ws, size_t ws_size,
                              hipStream_t stream) {
    const float* u0  = (const float*)d_in[0];
    const float* x   = (const float*)d_in[1];
    const float* nw1 = (const float*)d_in[2];
    const float* nb1 = (const float*)d_in[3];
    const float* nw2 = (const float*)d_in[4];
    const float* nb2 = (const float*)d_in[5];
    const float* ew1 = (const float*)d_in[6];
    const float* eb1 = (const float*)d_in[7];
    const float* ew2 = (const float*)d_in[8];
    const float* eb2 = (const float*)d_in[9];
    const float* cw1 = (const float*)d_in[10];
    const float* cb1 = (const float*)d_in[11];
    const float* cw2 = (const float*)d_in[12];
    const float* cb2 = (const float*)d_in[13];
    float* out = (float*)d_out;

    __hip_bfloat16* ws = (__hip_bfloat16*)d_ws;
    pack_weights<<<WS_TOTAL / 256, 256, 0, stream>>>(nw2, ew2, cw1, cw2, ws);

    const int grid = 16 * (NXc / Pc);   // 8192 blocks
    lifting_mfma<<<grid, NTc, 0, stream>>>(u0, x, nw1, nb1, nb2, eb1, eb2, cb1, cb2,
                                           ew1, (const short8*)d_ws, out);
}